// Round 1
// baseline (1274.639 us; speedup 1.0000x reference)
//
#include <hip/hip_runtime.h>

#define NODES 100000
#define EDGES 1600000

// ---------------- init: zero agg1, zero out, deg = 1 (self-loop) ------------
__global__ void k_init(float* __restrict__ agg1, float* __restrict__ out,
                       float* __restrict__ deg) {
  long long i = (long long)blockIdx.x * blockDim.x + threadIdx.x;
  if (i < (long long)NODES * 128) agg1[i] = 0.f;
  if (i < (long long)NODES * 64)  out[i]  = 0.f;
  if (i < NODES)                  deg[i]  = 1.f;
}

// ---------------- degree count over col --------------------------------------
__global__ void k_count(const int* __restrict__ col, float* __restrict__ deg) {
  int e = blockIdx.x * blockDim.x + threadIdx.x;
  if (e < EDGES) atomicAdd(&deg[col[e]], 1.f);
}

__global__ void k_dinv(float* __restrict__ deg) {
  int n = blockIdx.x * blockDim.x + threadIdx.x;
  if (n < NODES) deg[n] = 1.f / sqrtf(deg[n]);
}

// ---------------- f32 GEMM: H[n, FOUT] = X[n, 128] @ W[128, FOUT] ------------
// Block = 256 threads, tile ROWS x FOUT. W staged in LDS in two K-halves so
// static LDS stays <= 40KB. X tile staged in LDS.
template <int FOUT, int ROWS>
__global__ __launch_bounds__(256) void k_gemm(const float* __restrict__ X,
                                              const float* __restrict__ W,
                                              float* __restrict__ H, int nrows) {
  constexpr int RPT = ROWS * FOUT / 256;  // rows per thread
  __shared__ float Ws[64 * FOUT];
  __shared__ float Xs[ROWS][128];
  int r0 = blockIdx.x * ROWS;

  for (int i = threadIdx.x; i < ROWS * 128; i += 256) {
    int r = i >> 7, k = i & 127;
    int gr = r0 + r;
    Xs[r][k] = (gr < nrows) ? X[(long long)gr * 128 + k] : 0.f;
  }

  int c  = threadIdx.x % FOUT;
  int rg = threadIdx.x / FOUT;
  float acc[RPT];
#pragma unroll
  for (int i = 0; i < RPT; ++i) acc[i] = 0.f;

  for (int kh = 0; kh < 2; ++kh) {
    __syncthreads();  // protect Ws reuse
    for (int i = threadIdx.x; i < 64 * FOUT; i += 256) Ws[i] = W[kh * 64 * FOUT + i];
    __syncthreads();
#pragma unroll 4
    for (int k2 = 0; k2 < 64; ++k2) {
      float w = Ws[k2 * FOUT + c];
#pragma unroll
      for (int i = 0; i < RPT; ++i)
        acc[i] = fmaf(Xs[rg * RPT + i][kh * 64 + k2], w, acc[i]);
    }
  }

#pragma unroll
  for (int i = 0; i < RPT; ++i) {
    int gr = r0 + rg * RPT + i;
    if (gr < nrows) H[(long long)gr * FOUT + c] = acc[i];
  }
}

// ---------------- edge aggregation: agg[col] += H[row] * dinv[row]*dinv[col] -
// One wave (64 lanes) per edge; F/64 features per lane.
template <int F>
__global__ __launch_bounds__(256) void k_agg(const float* __restrict__ H,
                                             const int* __restrict__ rowi,
                                             const int* __restrict__ coli,
                                             const float* __restrict__ dinv,
                                             float* __restrict__ agg, int n_edges) {
  int lane = threadIdx.x & 63;
  int wid = blockIdx.x * (blockDim.x >> 6) + (threadIdx.x >> 6);
  int nwaves = gridDim.x * (blockDim.x >> 6);
  for (int e = wid; e < n_edges; e += nwaves) {
    int r = rowi[e], c = coli[e];
    float nrm = dinv[r] * dinv[c];
    const float* hr = H + (long long)r * F;
    float* ac = agg + (long long)c * F;
    if (F == 128) {
      float v0 = hr[lane] * nrm;
      float v1 = hr[64 + lane] * nrm;
      atomicAdd(&ac[lane], v0);
      atomicAdd(&ac[64 + lane], v1);
    } else {
      float v0 = hr[lane] * nrm;
      atomicAdd(&ac[lane], v0);
    }
  }
}

// ---------------- epilogue 1: h1r = relu(agg1 + h1*dinv^2 + b1) (in place) ---
__global__ void k_post1(float* __restrict__ agg1, const float* __restrict__ h1,
                        const float* __restrict__ dinv, const float* __restrict__ b1) {
  long long i = (long long)blockIdx.x * blockDim.x + threadIdx.x;
  if (i >= (long long)NODES * 128) return;
  int n = (int)(i >> 7), f = (int)(i & 127);
  float di = dinv[n];
  float v = agg1[i] + h1[i] * di * di + b1[f];
  agg1[i] = fmaxf(v, 0.f);
}

// ---------------- epilogue 2: out += h2*dinv^2 + b2 --------------------------
__global__ void k_post2(float* __restrict__ out, const float* __restrict__ h2,
                        const float* __restrict__ dinv, const float* __restrict__ b2) {
  long long i = (long long)blockIdx.x * blockDim.x + threadIdx.x;
  if (i >= (long long)NODES * 64) return;
  int n = (int)(i >> 6), f = (int)(i & 63);
  float di = dinv[n];
  out[i] += h2[i] * di * di + b2[f];
}

extern "C" void kernel_launch(void* const* d_in, const int* in_sizes, int n_in,
                              void* d_out, int out_size, void* d_ws, size_t ws_size,
                              hipStream_t stream) {
  const float* x  = (const float*)d_in[0];
  const int*   ei = (const int*)d_in[1];   // [2, E] flattened: row then col
  const float* W1 = (const float*)d_in[2];
  const float* b1 = (const float*)d_in[3];
  const float* W2 = (const float*)d_in[4];
  const float* b2 = (const float*)d_in[5];
  float* out = (float*)d_out;

  float* ws   = (float*)d_ws;
  float* deg  = ws;                  // NODES floats (becomes dinv in place)
  float* h1   = ws + 100352;         // NODES*128 floats (h2 reuses this)
  float* agg1 = h1 + (long long)NODES * 128;  // NODES*128 floats

  const int* rowi = ei;
  const int* coli = ei + EDGES;

  k_init<<<dim3((NODES * 128 + 255) / 256), dim3(256), 0, stream>>>(agg1, out, deg);
  k_count<<<dim3((EDGES + 255) / 256), dim3(256), 0, stream>>>(coli, deg);
  k_dinv<<<dim3((NODES + 255) / 256), dim3(256), 0, stream>>>(deg);

  // Layer 1
  k_gemm<128, 16><<<dim3((NODES + 15) / 16), dim3(256), 0, stream>>>(x, W1, h1, NODES);
  k_agg<128><<<dim3(16384), dim3(256), 0, stream>>>(h1, rowi, coli, deg, agg1, EDGES);
  k_post1<<<dim3((NODES * 128 + 255) / 256), dim3(256), 0, stream>>>(agg1, h1, deg, b1);

  // Layer 2 (h2 written into h1 buffer)
  k_gemm<64, 16><<<dim3((NODES + 15) / 16), dim3(256), 0, stream>>>(agg1, W2, h1, NODES);
  k_agg<64><<<dim3(16384), dim3(256), 0, stream>>>(h1, rowi, coli, deg, out, EDGES);
  k_post2<<<dim3((NODES * 64 + 255) / 256), dim3(256), 0, stream>>>(out, h1, deg, b2);
}

// Round 2
// 672.246 us; speedup vs baseline: 1.8961x; 1.8961x over previous
//
#include <hip/hip_runtime.h>

#define NODES 100000
#define EDGES 1600000
#define SCAN_BS 1024
#define SCAN_NB ((NODES + SCAN_BS - 1) / SCAN_BS)  // 98

// ---------------- degree count over col --------------------------------------
__global__ void k_count(const int* __restrict__ col, int* __restrict__ cnt) {
  int e = blockIdx.x * blockDim.x + threadIdx.x;
  if (e < EDGES) atomicAdd(&cnt[col[e]], 1);
}

// ---------------- scan stage 1: per-block exclusive scan + dinv --------------
__global__ __launch_bounds__(SCAN_BS) void k_scan1(const int* __restrict__ cnt,
                                                   int* __restrict__ offs,
                                                   int* __restrict__ partials,
                                                   float* __restrict__ dinv) {
  __shared__ int s[SCAN_BS];
  int i = blockIdx.x * SCAN_BS + threadIdx.x;
  int v = (i < NODES) ? cnt[i] : 0;
  if (i < NODES) dinv[i] = rsqrtf((float)(v + 1));  // +1 self-loop
  s[threadIdx.x] = v;
  __syncthreads();
  for (int d = 1; d < SCAN_BS; d <<= 1) {
    int t = (threadIdx.x >= d) ? s[threadIdx.x - d] : 0;
    __syncthreads();
    s[threadIdx.x] += t;
    __syncthreads();
  }
  if (i < NODES) offs[i] = s[threadIdx.x] - v;  // exclusive
  if (threadIdx.x == SCAN_BS - 1) partials[blockIdx.x] = s[SCAN_BS - 1];
}

// ---------------- scan stage 2: scan the 98 partials (one block) -------------
__global__ __launch_bounds__(128) void k_scan2(int* __restrict__ partials) {
  __shared__ int s[128];
  int v = (threadIdx.x < SCAN_NB) ? partials[threadIdx.x] : 0;
  s[threadIdx.x] = v;
  __syncthreads();
  for (int d = 1; d < 128; d <<= 1) {
    int t = (threadIdx.x >= d) ? s[threadIdx.x - d] : 0;
    __syncthreads();
    s[threadIdx.x] += t;
    __syncthreads();
  }
  if (threadIdx.x < SCAN_NB) partials[threadIdx.x] = s[threadIdx.x] - v;  // exclusive
}

// ---------------- scan stage 3: add block offsets, copy cursor ---------------
__global__ __launch_bounds__(SCAN_BS) void k_scan3(int* __restrict__ offs,
                                                   const int* __restrict__ partials,
                                                   int* __restrict__ cursor) {
  int i = blockIdx.x * SCAN_BS + threadIdx.x;
  if (i < NODES) {
    int o = offs[i] + partials[blockIdx.x];
    offs[i] = o;
    cursor[i] = o;
  }
}

// ---------------- scatter edges into CSR segments ----------------------------
__global__ void k_scatter(const int* __restrict__ rowi, const int* __restrict__ coli,
                          int* __restrict__ cursor, int* __restrict__ srow) {
  int e = blockIdx.x * blockDim.x + threadIdx.x;
  if (e < EDGES) {
    int c = coli[e];
    int p = atomicAdd(&cursor[c], 1);
    srow[p] = rowi[e];
  }
}

// ---------------- f32 GEMM with dinv epilogue: HD[n] = (X[n]@W) * dinv[n] ----
template <int FOUT, int ROWS>
__global__ __launch_bounds__(256) void k_gemm(const float* __restrict__ X,
                                              const float* __restrict__ W,
                                              const float* __restrict__ dinv,
                                              float* __restrict__ HD, int nrows) {
  constexpr int RPT = ROWS * FOUT / 256;  // rows per thread
  __shared__ float Ws[64 * FOUT];
  __shared__ float Xs[ROWS][128];
  int r0 = blockIdx.x * ROWS;

  for (int i = threadIdx.x; i < ROWS * 128; i += 256) {
    int r = i >> 7, k = i & 127;
    int gr = r0 + r;
    Xs[r][k] = (gr < nrows) ? X[(long long)gr * 128 + k] : 0.f;
  }

  int c  = threadIdx.x % FOUT;
  int rg = threadIdx.x / FOUT;
  float acc[RPT];
#pragma unroll
  for (int i = 0; i < RPT; ++i) acc[i] = 0.f;

  for (int kh = 0; kh < 2; ++kh) {
    __syncthreads();
    for (int i = threadIdx.x; i < 64 * FOUT; i += 256) Ws[i] = W[kh * 64 * FOUT + i];
    __syncthreads();
#pragma unroll 4
    for (int k2 = 0; k2 < 64; ++k2) {
      float w = Ws[k2 * FOUT + c];
#pragma unroll
      for (int i = 0; i < RPT; ++i)
        acc[i] = fmaf(Xs[rg * RPT + i][kh * 64 + k2], w, acc[i]);
    }
  }

#pragma unroll
  for (int i = 0; i < RPT; ++i) {
    int gr = r0 + rg * RPT + i;
    if (gr < nrows) HD[(long long)gr * FOUT + c] = acc[i] * dinv[gr];
  }
}

// ---------------- CSR aggregation, F=128: one wave per node ------------------
// out1[c] = relu((hd[c] + sum_{r in N(c)} hd[r]) * dinv[c] + b1)
__global__ __launch_bounds__(256) void k_agg1(const float* __restrict__ hd,
                                              const int* __restrict__ srow,
                                              const int* __restrict__ offs,
                                              const int* __restrict__ cnt,
                                              const float* __restrict__ dinv,
                                              const float* __restrict__ b1,
                                              float* __restrict__ outp) {
  int w = (blockIdx.x << 2) + (threadIdx.x >> 6);
  if (w >= NODES) return;
  int lane = threadIdx.x & 63;
  const float2* H = (const float2*)hd;
  float2 acc = H[(long long)w * 64 + lane];  // self-loop term hd[c]
  int off = offs[w], n = cnt[w];
  int r = (n > 0) ? srow[off] : 0;
  for (int j = 0; j < n; ++j) {
    int rn = (j + 1 < n) ? srow[off + j + 1] : 0;
    float2 v = H[(long long)r * 64 + lane];
    acc.x += v.x;
    acc.y += v.y;
    r = rn;
  }
  float dc = dinv[w];
  float2 b = ((const float2*)b1)[lane];
  float2 o;
  o.x = fmaxf(fmaf(acc.x, dc, b.x), 0.f);
  o.y = fmaxf(fmaf(acc.y, dc, b.y), 0.f);
  ((float2*)outp)[(long long)w * 64 + lane] = o;
}

// ---------------- CSR aggregation, F=64 (final layer, no relu) ---------------
__global__ __launch_bounds__(256) void k_agg2(const float* __restrict__ hd,
                                              const int* __restrict__ srow,
                                              const int* __restrict__ offs,
                                              const int* __restrict__ cnt,
                                              const float* __restrict__ dinv,
                                              const float* __restrict__ b2,
                                              float* __restrict__ outp) {
  int w = (blockIdx.x << 2) + (threadIdx.x >> 6);
  if (w >= NODES) return;
  int lane = threadIdx.x & 63;
  float acc = hd[(long long)w * 64 + lane];  // self-loop
  int off = offs[w], n = cnt[w];
  int r = (n > 0) ? srow[off] : 0;
  for (int j = 0; j < n; ++j) {
    int rn = (j + 1 < n) ? srow[off + j + 1] : 0;
    acc += hd[(long long)r * 64 + lane];
    r = rn;
  }
  outp[(long long)w * 64 + lane] = fmaf(acc, dinv[w], b2[lane]);
}

extern "C" void kernel_launch(void* const* d_in, const int* in_sizes, int n_in,
                              void* d_out, int out_size, void* d_ws, size_t ws_size,
                              hipStream_t stream) {
  const float* x  = (const float*)d_in[0];
  const int*   ei = (const int*)d_in[1];  // [2, E]: row then col
  const float* W1 = (const float*)d_in[2];
  const float* b1 = (const float*)d_in[3];
  const float* W2 = (const float*)d_in[4];
  const float* b2 = (const float*)d_in[5];
  float* out = (float*)d_out;

  float* ws       = (float*)d_ws;
  float* dinv     = ws;                       // NODES (padded 100352)
  int*   cnt      = (int*)(ws + 100352);      // NODES
  int*   offs     = cnt + 100352;             // NODES
  int*   cursor   = offs + 100352;            // NODES
  int*   partials = cursor + 100352;          // 256
  int*   srow     = partials + 256;           // EDGES
  float* hd       = (float*)(srow + EDGES);   // NODES*128 (layer2 reuses)
  float* h1r      = hd + (long long)NODES * 128;  // NODES*128

  const int* rowi = ei;
  const int* coli = ei + EDGES;

  // ---- CSR build (shared by both layers) ----
  hipMemsetAsync(cnt, 0, NODES * sizeof(int), stream);
  k_count<<<dim3((EDGES + 255) / 256), dim3(256), 0, stream>>>(coli, cnt);
  k_scan1<<<dim3(SCAN_NB), dim3(SCAN_BS), 0, stream>>>(cnt, offs, partials, dinv);
  k_scan2<<<dim3(1), dim3(128), 0, stream>>>(partials);
  k_scan3<<<dim3(SCAN_NB), dim3(SCAN_BS), 0, stream>>>(offs, partials, cursor);
  k_scatter<<<dim3((EDGES + 255) / 256), dim3(256), 0, stream>>>(rowi, coli, cursor, srow);

  // ---- Layer 1 ----
  k_gemm<128, 16><<<dim3((NODES + 15) / 16), dim3(256), 0, stream>>>(x, W1, dinv, hd, NODES);
  k_agg1<<<dim3((NODES + 3) / 4), dim3(256), 0, stream>>>(hd, srow, offs, cnt, dinv, b1, h1r);

  // ---- Layer 2 ----
  k_gemm<64, 16><<<dim3((NODES + 15) / 16), dim3(256), 0, stream>>>(h1r, W2, dinv, hd, NODES);
  k_agg2<<<dim3((NODES + 3) / 4), dim3(256), 0, stream>>>(hd, srow, offs, cnt, dinv, b2, out);
}

// Round 3
// 479.855 us; speedup vs baseline: 2.6563x; 1.4009x over previous
//
#include <hip/hip_runtime.h>

#define NODES 100000
#define EDGES 1600000
#define SCAN_BS 1024
#define SCAN_NB ((NODES + SCAN_BS - 1) / SCAN_BS)  // 98

// ---------------- degree count over col --------------------------------------
__global__ void k_count(const int* __restrict__ col, int* __restrict__ cnt) {
  int e = blockIdx.x * blockDim.x + threadIdx.x;
  if (e < EDGES) atomicAdd(&cnt[col[e]], 1);
}

// ---------------- scan stage 1: per-block exclusive scan + dinv --------------
__global__ __launch_bounds__(SCAN_BS) void k_scan1(const int* __restrict__ cnt,
                                                   int* __restrict__ offs,
                                                   int* __restrict__ partials,
                                                   float* __restrict__ dinv) {
  __shared__ int s[SCAN_BS];
  int i = blockIdx.x * SCAN_BS + threadIdx.x;
  int v = (i < NODES) ? cnt[i] : 0;
  if (i < NODES) dinv[i] = rsqrtf((float)(v + 1));  // +1 self-loop
  s[threadIdx.x] = v;
  __syncthreads();
  for (int d = 1; d < SCAN_BS; d <<= 1) {
    int t = (threadIdx.x >= d) ? s[threadIdx.x - d] : 0;
    __syncthreads();
    s[threadIdx.x] += t;
    __syncthreads();
  }
  if (i < NODES) offs[i] = s[threadIdx.x] - v;  // exclusive
  if (threadIdx.x == SCAN_BS - 1) partials[blockIdx.x] = s[SCAN_BS - 1];
}

// ---------------- scan stage 2: scan the 98 partials (one block) -------------
__global__ __launch_bounds__(128) void k_scan2(int* __restrict__ partials) {
  __shared__ int s[128];
  int v = (threadIdx.x < SCAN_NB) ? partials[threadIdx.x] : 0;
  s[threadIdx.x] = v;
  __syncthreads();
  for (int d = 1; d < 128; d <<= 1) {
    int t = (threadIdx.x >= d) ? s[threadIdx.x - d] : 0;
    __syncthreads();
    s[threadIdx.x] += t;
    __syncthreads();
  }
  if (threadIdx.x < SCAN_NB) partials[threadIdx.x] = s[threadIdx.x] - v;  // exclusive
}

// ---------------- scan stage 3: add block offsets, copy cursor ---------------
__global__ __launch_bounds__(SCAN_BS) void k_scan3(int* __restrict__ offs,
                                                   const int* __restrict__ partials,
                                                   int* __restrict__ cursor) {
  int i = blockIdx.x * SCAN_BS + threadIdx.x;
  if (i < NODES) {
    int o = offs[i] + partials[blockIdx.x];
    offs[i] = o;
    cursor[i] = o;
  }
}

// ---------------- scatter edges into CSR segments ----------------------------
__global__ void k_scatter(const int* __restrict__ rowi, const int* __restrict__ coli,
                          int* __restrict__ cursor, int* __restrict__ srow) {
  int e = blockIdx.x * blockDim.x + threadIdx.x;
  if (e < EDGES) {
    int c = coli[e];
    int p = atomicAdd(&cursor[c], 1);
    srow[p] = rowi[e];
  }
}

// ---------------- register-tiled f32 GEMM: HD[n] = (X[n,128]@W) * dinv[n] ----
// Block = 256 threads (tx 0..15, ty 0..15), tile ROWS x FOUT.
// Thread computes RPT rows x CPT cols (32 outputs). K chunked by 32.
template <int FOUT, int ROWS>
__global__ __launch_bounds__(256) void k_gemm(const float* __restrict__ X,
                                              const float* __restrict__ W,
                                              const float* __restrict__ dinv,
                                              float* __restrict__ HD, int nrows) {
  constexpr int RPT = ROWS / 16;   // 4 (FOUT=128) or 8 (FOUT=64)
  constexpr int CPT = FOUT / 16;   // 8 or 4
  constexpr int NQ  = CPT / 4;     // float4s per thread per k: 2 or 1
  __shared__ float Ws[32 * FOUT];
  __shared__ float Xs[ROWS][33];   // +1 pad: kills ty-stride bank conflicts

  const int tx = threadIdx.x & 15;
  const int ty = threadIdx.x >> 4;
  const int r0 = blockIdx.x * ROWS;

  float acc[RPT][CPT];
#pragma unroll
  for (int i = 0; i < RPT; ++i)
#pragma unroll
    for (int j = 0; j < CPT; ++j) acc[i][j] = 0.f;

  for (int kc = 0; kc < 4; ++kc) {
    // stage W chunk [32][FOUT] (linear copy, float4)
    const float4* W4 = (const float4*)(W + kc * 32 * FOUT);
    float4* Ws4 = (float4*)Ws;
    for (int i = threadIdx.x; i < 32 * FOUT / 4; i += 256) Ws4[i] = W4[i];
    // stage X chunk [ROWS][32]
    for (int i = threadIdx.x; i < ROWS * 8; i += 256) {
      int r = i >> 3, k4 = (i & 7) << 2;
      int gr = r0 + r;
      float4 v = (gr < nrows) ? *(const float4*)(X + (long long)gr * 128 + kc * 32 + k4)
                              : make_float4(0.f, 0.f, 0.f, 0.f);
      Xs[r][k4 + 0] = v.x; Xs[r][k4 + 1] = v.y; Xs[r][k4 + 2] = v.z; Xs[r][k4 + 3] = v.w;
    }
    __syncthreads();

#pragma unroll 8
    for (int k2 = 0; k2 < 32; ++k2) {
      float xv[RPT];
#pragma unroll
      for (int i = 0; i < RPT; ++i) xv[i] = Xs[ty * RPT + i][k2];
      float4 wv[NQ];
#pragma unroll
      for (int q = 0; q < NQ; ++q)
        wv[q] = *(const float4*)(Ws + k2 * FOUT + q * 64 + tx * 4);
#pragma unroll
      for (int i = 0; i < RPT; ++i)
#pragma unroll
        for (int q = 0; q < NQ; ++q) {
          acc[i][q * 4 + 0] = fmaf(xv[i], wv[q].x, acc[i][q * 4 + 0]);
          acc[i][q * 4 + 1] = fmaf(xv[i], wv[q].y, acc[i][q * 4 + 1]);
          acc[i][q * 4 + 2] = fmaf(xv[i], wv[q].z, acc[i][q * 4 + 2]);
          acc[i][q * 4 + 3] = fmaf(xv[i], wv[q].w, acc[i][q * 4 + 3]);
        }
    }
    __syncthreads();
  }

#pragma unroll
  for (int i = 0; i < RPT; ++i) {
    int gr = r0 + ty * RPT + i;
    if (gr < nrows) {
      float d = dinv[gr];
#pragma unroll
      for (int q = 0; q < NQ; ++q) {
        float4 o;
        o.x = acc[i][q * 4 + 0] * d; o.y = acc[i][q * 4 + 1] * d;
        o.z = acc[i][q * 4 + 2] * d; o.w = acc[i][q * 4 + 3] * d;
        *(float4*)(HD + (long long)gr * FOUT + q * 64 + tx * 4) = o;
      }
    }
  }
}

// ---------------- CSR aggregation, F=128: one wave per node ------------------
// out1[c] = relu((hd[c] + sum_{r in N(c)} hd[r]) * dinv[c] + b1)
// 4 independent accumulators -> 4 gathers in flight per lane.
__global__ __launch_bounds__(256) void k_agg1(const float* __restrict__ hd,
                                              const int* __restrict__ srow,
                                              const int* __restrict__ offs,
                                              const int* __restrict__ cnt,
                                              const float* __restrict__ dinv,
                                              const float* __restrict__ b1,
                                              float* __restrict__ outp) {
  int w = (blockIdx.x << 2) + (threadIdx.x >> 6);
  if (w >= NODES) return;
  int lane = threadIdx.x & 63;
  const float2* H = (const float2*)hd;
  float2 a0 = H[(long long)w * 64 + lane];  // self-loop term hd[c]
  float2 a1 = make_float2(0.f, 0.f), a2 = make_float2(0.f, 0.f), a3 = make_float2(0.f, 0.f);
  int off = offs[w], n = cnt[w];
  int j = 0;
  for (; j + 3 < n; j += 4) {
    int r0 = srow[off + j], r1 = srow[off + j + 1];
    int r2 = srow[off + j + 2], r3 = srow[off + j + 3];
    float2 v0 = H[(long long)r0 * 64 + lane];
    float2 v1 = H[(long long)r1 * 64 + lane];
    float2 v2 = H[(long long)r2 * 64 + lane];
    float2 v3 = H[(long long)r3 * 64 + lane];
    a0.x += v0.x; a0.y += v0.y;
    a1.x += v1.x; a1.y += v1.y;
    a2.x += v2.x; a2.y += v2.y;
    a3.x += v3.x; a3.y += v3.y;
  }
  for (; j < n; ++j) {
    float2 v = H[(long long)srow[off + j] * 64 + lane];
    a0.x += v.x; a0.y += v.y;
  }
  float2 acc;
  acc.x = (a0.x + a1.x) + (a2.x + a3.x);
  acc.y = (a0.y + a1.y) + (a2.y + a3.y);
  float dc = dinv[w];
  float2 b = ((const float2*)b1)[lane];
  float2 o;
  o.x = fmaxf(fmaf(acc.x, dc, b.x), 0.f);
  o.y = fmaxf(fmaf(acc.y, dc, b.y), 0.f);
  ((float2*)outp)[(long long)w * 64 + lane] = o;
}

// ---------------- CSR aggregation, F=64 (final layer, no relu) ---------------
__global__ __launch_bounds__(256) void k_agg2(const float* __restrict__ hd,
                                              const int* __restrict__ srow,
                                              const int* __restrict__ offs,
                                              const int* __restrict__ cnt,
                                              const float* __restrict__ dinv,
                                              const float* __restrict__ b2,
                                              float* __restrict__ outp) {
  int w = (blockIdx.x << 2) + (threadIdx.x >> 6);
  if (w >= NODES) return;
  int lane = threadIdx.x & 63;
  float a0 = hd[(long long)w * 64 + lane];  // self-loop
  float a1 = 0.f, a2 = 0.f, a3 = 0.f;
  int off = offs[w], n = cnt[w];
  int j = 0;
  for (; j + 3 < n; j += 4) {
    int r0 = srow[off + j], r1 = srow[off + j + 1];
    int r2 = srow[off + j + 2], r3 = srow[off + j + 3];
    a0 += hd[(long long)r0 * 64 + lane];
    a1 += hd[(long long)r1 * 64 + lane];
    a2 += hd[(long long)r2 * 64 + lane];
    a3 += hd[(long long)r3 * 64 + lane];
  }
  for (; j < n; ++j) a0 += hd[(long long)srow[off + j] * 64 + lane];
  float acc = (a0 + a1) + (a2 + a3);
  outp[(long long)w * 64 + lane] = fmaf(acc, dinv[w], b2[lane]);
}

extern "C" void kernel_launch(void* const* d_in, const int* in_sizes, int n_in,
                              void* d_out, int out_size, void* d_ws, size_t ws_size,
                              hipStream_t stream) {
  const float* x  = (const float*)d_in[0];
  const int*   ei = (const int*)d_in[1];  // [2, E]: row then col
  const float* W1 = (const float*)d_in[2];
  const float* b1 = (const float*)d_in[3];
  const float* W2 = (const float*)d_in[4];
  const float* b2 = (const float*)d_in[5];
  float* out = (float*)d_out;

  float* ws       = (float*)d_ws;
  float* dinv     = ws;                       // NODES (padded 100352)
  int*   cnt      = (int*)(ws + 100352);      // NODES
  int*   offs     = cnt + 100352;             // NODES
  int*   cursor   = offs + 100352;            // NODES
  int*   partials = cursor + 100352;          // 256
  int*   srow     = partials + 256;           // EDGES
  float* hd       = (float*)(srow + EDGES);   // NODES*128 (layer2 reuses)
  float* h1r      = hd + (long long)NODES * 128;  // NODES*128

  const int* rowi = ei;
  const int* coli = ei + EDGES;

  // ---- CSR build (shared by both layers) ----
  hipMemsetAsync(cnt, 0, NODES * sizeof(int), stream);
  k_count<<<dim3((EDGES + 255) / 256), dim3(256), 0, stream>>>(coli, cnt);
  k_scan1<<<dim3(SCAN_NB), dim3(SCAN_BS), 0, stream>>>(cnt, offs, partials, dinv);
  k_scan2<<<dim3(1), dim3(128), 0, stream>>>(partials);
  k_scan3<<<dim3(SCAN_NB), dim3(SCAN_BS), 0, stream>>>(offs, partials, cursor);
  k_scatter<<<dim3((EDGES + 255) / 256), dim3(256), 0, stream>>>(rowi, coli, cursor, srow);

  // ---- Layer 1 ----
  k_gemm<128, 64><<<dim3((NODES + 63) / 64), dim3(256), 0, stream>>>(x, W1, dinv, hd, NODES);
  k_agg1<<<dim3((NODES + 3) / 4), dim3(256), 0, stream>>>(hd, srow, offs, cnt, dinv, b1, h1r);

  // ---- Layer 2 ----
  k_gemm<64, 128><<<dim3((NODES + 127) / 128), dim3(256), 0, stream>>>(h1r, W2, dinv, hd, NODES);
  k_agg2<<<dim3((NODES + 3) / 4), dim3(256), 0, stream>>>(hd, srow, offs, cnt, dinv, b2, out);
}

// Round 4
// 273.091 us; speedup vs baseline: 4.6674x; 1.7571x over previous
//
#include <hip/hip_runtime.h>

#define NODES 100000
#define EDGES 1600000
#define NB1 196          // number of col buckets: ceil(100000/512)
#define CAPB 10240       // per-bucket edge capacity (mean 8192, sigma ~90)

// ---- bf16 helpers (RNE) -----------------------------------------------------
__device__ __forceinline__ unsigned short f2bf(float f) {
  unsigned int u = __float_as_uint(f);
  return (unsigned short)((u + 0x7fffu + ((u >> 16) & 1u)) >> 16);
}
__device__ __forceinline__ float bf2f(unsigned short b) {
  return __uint_as_float(((unsigned int)b) << 16);
}
__device__ __forceinline__ float2 up2(unsigned int u) {
  float2 f;
  f.x = __uint_as_float(u << 16);          // low ushort = even element
  f.y = __uint_as_float(u & 0xffff0000u);  // high ushort = odd element
  return f;
}

// ---- init bucket cursors ----------------------------------------------------
__global__ void k_binit(int* __restrict__ bcur) {
  int k = threadIdx.x;
  if (k < NB1) bcur[k] = k * CAPB;
}

// ---- S1: bin edges by col>>9 into fixed-stride bucket regions ---------------
// Block = 256 threads x 16 edges. LDS histogram -> one global atomic per
// (block,bucket) reserves a dense run -> writes are line-dense.
__global__ __launch_bounds__(256) void kS1(const int* __restrict__ rowi,
                                           const int* __restrict__ coli,
                                           int* __restrict__ bcur,
                                           int2* __restrict__ binbuf) {
  __shared__ int hist[NB1];
  __shared__ int base[NB1];
  const int t = threadIdx.x;
  const long long e0 = (long long)blockIdx.x * 4096;
  for (int i = t; i < NB1; i += 256) hist[i] = 0;
  __syncthreads();
  int r[16], c[16], b[16];
#pragma unroll
  for (int i = 0; i < 16; ++i) {
    long long e = e0 + t + i * 256;
    if (e < EDGES) {
      r[i] = rowi[e]; c[i] = coli[e]; b[i] = c[i] >> 9;
      atomicAdd(&hist[b[i]], 1);
    } else {
      b[i] = -1;
    }
  }
  __syncthreads();
  for (int i = t; i < NB1; i += 256)
    base[i] = hist[i] ? atomicAdd(&bcur[i], hist[i]) : 0;
  __syncthreads();
#pragma unroll
  for (int i = 0; i < 16; ++i) {
    if (b[i] >= 0) {
      int p = atomicAdd(&base[b[i]], 1);
      if (p < (b[i] + 1) * CAPB)  // overflow guard (practically never)
        binbuf[p] = make_int2(r[i], c[i]);
    }
  }
}

// ---- S2: per-bucket 512-col histogram + scan + LDS-cursor sort --------------
// Produces offs/cnt/dinv AND srow. One block per bucket.
__global__ __launch_bounds__(256) void kS2(const int2* __restrict__ binbuf,
                                           const int* __restrict__ bcur,
                                           int* __restrict__ srow,
                                           int* __restrict__ offs,
                                           int* __restrict__ cnt,
                                           float* __restrict__ dinv) {
  __shared__ int h[512];
  __shared__ int sc[256];
  const int k = blockIdx.x, t = threadIdx.x;
  const int beg = k * CAPB;
  const int c0 = k << 9;
  int n = bcur[k] - beg;
  if (n > CAPB) n = CAPB;
  h[t] = 0; h[t + 256] = 0;
  __syncthreads();
  for (int i = t; i < n; i += 256) atomicAdd(&h[binbuf[beg + i].y - c0], 1);
  __syncthreads();
  int s0 = h[2 * t], s1 = h[2 * t + 1];
  sc[t] = s0 + s1;
  __syncthreads();
  for (int d = 1; d < 256; d <<= 1) {
    int v = (t >= d) ? sc[t - d] : 0;
    __syncthreads();
    sc[t] += v;
    __syncthreads();
  }
  int base2 = t ? sc[t - 1] : 0;  // exclusive over pairs
  int c = c0 + 2 * t;
  if (c < NODES) {
    offs[c] = beg + base2; cnt[c] = s0; dinv[c] = rsqrtf((float)(s0 + 1));
  }
  if (c + 1 < NODES) {
    offs[c + 1] = beg + base2 + s0; cnt[c + 1] = s1; dinv[c + 1] = rsqrtf((float)(s1 + 1));
  }
  __syncthreads();
  h[2 * t] = beg + base2;          // reuse h as global-position cursor
  h[2 * t + 1] = beg + base2 + s0;
  __syncthreads();
  for (int i = t; i < n; i += 256) {
    int2 p = binbuf[beg + i];
    int pos = atomicAdd(&h[p.y - c0], 1);
    srow[pos] = p.x;  // dense 32KB region per block
  }
}

// ---- register-tiled f32 GEMM: HD[n] = bf16((X[n,128]@W) * dinv[n]) ----------
template <int FOUT, int ROWS>
__global__ __launch_bounds__(256) void k_gemm(const float* __restrict__ X,
                                              const float* __restrict__ W,
                                              const float* __restrict__ dinv,
                                              unsigned short* __restrict__ HD,
                                              int nrows) {
  constexpr int RPT = ROWS / 16;
  constexpr int CPT = FOUT / 16;
  constexpr int NQ  = CPT / 4;
  __shared__ float Ws[32 * FOUT];
  __shared__ float Xs[ROWS][33];

  const int tx = threadIdx.x & 15;
  const int ty = threadIdx.x >> 4;
  const int r0 = blockIdx.x * ROWS;

  float acc[RPT][CPT];
#pragma unroll
  for (int i = 0; i < RPT; ++i)
#pragma unroll
    for (int j = 0; j < CPT; ++j) acc[i][j] = 0.f;

  for (int kc = 0; kc < 4; ++kc) {
    const float4* W4 = (const float4*)(W + kc * 32 * FOUT);
    float4* Ws4 = (float4*)Ws;
    for (int i = threadIdx.x; i < 32 * FOUT / 4; i += 256) Ws4[i] = W4[i];
    for (int i = threadIdx.x; i < ROWS * 8; i += 256) {
      int r = i >> 3, k4 = (i & 7) << 2;
      int gr = r0 + r;
      float4 v = (gr < nrows) ? *(const float4*)(X + (long long)gr * 128 + kc * 32 + k4)
                              : make_float4(0.f, 0.f, 0.f, 0.f);
      Xs[r][k4 + 0] = v.x; Xs[r][k4 + 1] = v.y; Xs[r][k4 + 2] = v.z; Xs[r][k4 + 3] = v.w;
    }
    __syncthreads();

#pragma unroll 8
    for (int k2 = 0; k2 < 32; ++k2) {
      float xv[RPT];
#pragma unroll
      for (int i = 0; i < RPT; ++i) xv[i] = Xs[ty * RPT + i][k2];
      float4 wv[NQ];
#pragma unroll
      for (int q = 0; q < NQ; ++q)
        wv[q] = *(const float4*)(Ws + k2 * FOUT + q * 64 + tx * 4);
#pragma unroll
      for (int i = 0; i < RPT; ++i)
#pragma unroll
        for (int q = 0; q < NQ; ++q) {
          acc[i][q * 4 + 0] = fmaf(xv[i], wv[q].x, acc[i][q * 4 + 0]);
          acc[i][q * 4 + 1] = fmaf(xv[i], wv[q].y, acc[i][q * 4 + 1]);
          acc[i][q * 4 + 2] = fmaf(xv[i], wv[q].z, acc[i][q * 4 + 2]);
          acc[i][q * 4 + 3] = fmaf(xv[i], wv[q].w, acc[i][q * 4 + 3]);
        }
    }
    __syncthreads();
  }

#pragma unroll
  for (int i = 0; i < RPT; ++i) {
    int gr = r0 + ty * RPT + i;
    if (gr < nrows) {
      float d = dinv[gr];
#pragma unroll
      for (int q = 0; q < NQ; ++q) {
        ushort4 o;
        o.x = f2bf(acc[i][q * 4 + 0] * d);
        o.y = f2bf(acc[i][q * 4 + 1] * d);
        o.z = f2bf(acc[i][q * 4 + 2] * d);
        o.w = f2bf(acc[i][q * 4 + 3] * d);
        *(ushort4*)(HD + (long long)gr * FOUT + q * 64 + tx * 4) = o;
      }
    }
  }
}

// ---- CSR aggregation, F=128 bf16 in / f32 out (relu+bias) -------------------
__global__ __launch_bounds__(256) void k_agg1(const unsigned short* __restrict__ hd,
                                              const int* __restrict__ srow,
                                              const int* __restrict__ offs,
                                              const int* __restrict__ cnt,
                                              const float* __restrict__ dinv,
                                              const float* __restrict__ b1,
                                              float* __restrict__ outp) {
  int w = (blockIdx.x << 2) + (threadIdx.x >> 6);
  if (w >= NODES) return;
  int lane = threadIdx.x & 63;
  const unsigned int* H = (const unsigned int*)hd;  // 2 bf16 per uint, 64/row
  float2 a0 = up2(H[(long long)w * 64 + lane]);     // self-loop term
  float2 a1 = make_float2(0.f, 0.f), a2 = make_float2(0.f, 0.f), a3 = make_float2(0.f, 0.f);
  int off = offs[w], n = cnt[w];
  int j = 0;
  for (; j + 3 < n; j += 4) {
    int r0 = srow[off + j], r1 = srow[off + j + 1];
    int r2 = srow[off + j + 2], r3 = srow[off + j + 3];
    float2 v0 = up2(H[(long long)r0 * 64 + lane]);
    float2 v1 = up2(H[(long long)r1 * 64 + lane]);
    float2 v2 = up2(H[(long long)r2 * 64 + lane]);
    float2 v3 = up2(H[(long long)r3 * 64 + lane]);
    a0.x += v0.x; a0.y += v0.y;
    a1.x += v1.x; a1.y += v1.y;
    a2.x += v2.x; a2.y += v2.y;
    a3.x += v3.x; a3.y += v3.y;
  }
  for (; j < n; ++j) {
    float2 v = up2(H[(long long)srow[off + j] * 64 + lane]);
    a0.x += v.x; a0.y += v.y;
  }
  float2 acc;
  acc.x = (a0.x + a1.x) + (a2.x + a3.x);
  acc.y = (a0.y + a1.y) + (a2.y + a3.y);
  float dc = dinv[w];
  float2 b = ((const float2*)b1)[lane];
  float2 o;
  o.x = fmaxf(fmaf(acc.x, dc, b.x), 0.f);
  o.y = fmaxf(fmaf(acc.y, dc, b.y), 0.f);
  ((float2*)outp)[(long long)w * 64 + lane] = o;
}

// ---- CSR aggregation, F=64 bf16 in / f32 out (final, no relu) ---------------
__global__ __launch_bounds__(256) void k_agg2(const unsigned short* __restrict__ hd,
                                              const int* __restrict__ srow,
                                              const int* __restrict__ offs,
                                              const int* __restrict__ cnt,
                                              const float* __restrict__ dinv,
                                              const float* __restrict__ b2,
                                              float* __restrict__ outp) {
  int w = (blockIdx.x << 2) + (threadIdx.x >> 6);
  if (w >= NODES) return;
  int lane = threadIdx.x & 63;
  float a0 = bf2f(hd[(long long)w * 64 + lane]);  // self-loop
  float a1 = 0.f, a2 = 0.f, a3 = 0.f;
  int off = offs[w], n = cnt[w];
  int j = 0;
  for (; j + 3 < n; j += 4) {
    int r0 = srow[off + j], r1 = srow[off + j + 1];
    int r2 = srow[off + j + 2], r3 = srow[off + j + 3];
    a0 += bf2f(hd[(long long)r0 * 64 + lane]);
    a1 += bf2f(hd[(long long)r1 * 64 + lane]);
    a2 += bf2f(hd[(long long)r2 * 64 + lane]);
    a3 += bf2f(hd[(long long)r3 * 64 + lane]);
  }
  for (; j < n; ++j) a0 += bf2f(hd[(long long)srow[off + j] * 64 + lane]);
  float acc = (a0 + a1) + (a2 + a3);
  outp[(long long)w * 64 + lane] = fmaf(acc, dinv[w], b2[lane]);
}

extern "C" void kernel_launch(void* const* d_in, const int* in_sizes, int n_in,
                              void* d_out, int out_size, void* d_ws, size_t ws_size,
                              hipStream_t stream) {
  const float* x  = (const float*)d_in[0];
  const int*   ei = (const int*)d_in[1];  // [2, E]: row then col
  const float* W1 = (const float*)d_in[2];
  const float* b1 = (const float*)d_in[3];
  const float* W2 = (const float*)d_in[4];
  const float* b2 = (const float*)d_in[5];
  float* out = (float*)d_out;

  float* ws   = (float*)d_ws;
  float* dinv = ws;                        // 100352 f
  int*  cnt   = (int*)(ws + 100352);       // 100352 i
  int*  offs  = cnt + 100352;              // 100352 i
  int*  bcur  = offs + 100352;             // 256 i
  int*  srow  = bcur + 256;                // NB1*CAPB = 2007040 i
  int2* binbuf = (int2*)(srow + NB1 * CAPB);              // NB1*CAPB int2 (16MB)
  unsigned short* hd = (unsigned short*)(binbuf + NB1 * CAPB);  // NODES*128 bf16
  float* h1r  = (float*)(hd + (long long)NODES * 128);    // NODES*128 f32

  const int* rowi = ei;
  const int* coli = ei + EDGES;

  // ---- CSR build ----
  k_binit<<<dim3(1), dim3(256), 0, stream>>>(bcur);
  kS1<<<dim3((EDGES + 4095) / 4096), dim3(256), 0, stream>>>(rowi, coli, bcur, binbuf);
  kS2<<<dim3(NB1), dim3(256), 0, stream>>>(binbuf, bcur, srow, offs, cnt, dinv);

  // ---- Layer 1 ----
  k_gemm<128, 64><<<dim3((NODES + 63) / 64), dim3(256), 0, stream>>>(x, W1, dinv, hd, NODES);
  k_agg1<<<dim3((NODES + 3) / 4), dim3(256), 0, stream>>>(hd, srow, offs, cnt, dinv, b1, h1r);

  // ---- Layer 2 ----
  k_gemm<64, 128><<<dim3((NODES + 127) / 128), dim3(256), 0, stream>>>(h1r, W2, dinv, hd, NODES);
  k_agg2<<<dim3((NODES + 3) / 4), dim3(256), 0, stream>>>(hd, srow, offs, cnt, dinv, b2, out);
}

// Round 5
// 215.225 us; speedup vs baseline: 5.9224x; 1.2689x over previous
//
#include <hip/hip_runtime.h>

#define NODES 100000
#define EDGES 1600000
#define NB1 196          // col buckets: ceil(100000/512)
#define CAPB 10240       // per-bucket edge capacity (mean 8192)

typedef __attribute__((ext_vector_type(8))) short short8;
typedef __attribute__((ext_vector_type(4))) float f32x4;

// ---- bf16 helpers (RNE) -----------------------------------------------------
__device__ __forceinline__ unsigned short f2bf(float f) {
  unsigned int u = __float_as_uint(f);
  return (unsigned short)((u + 0x7fffu + ((u >> 16) & 1u)) >> 16);
}
__device__ __forceinline__ float bf2f(unsigned short b) {
  return __uint_as_float(((unsigned int)b) << 16);
}
__device__ __forceinline__ float2 up2(unsigned int u) {
  float2 f;
  f.x = __uint_as_float(u << 16);
  f.y = __uint_as_float(u & 0xffff0000u);
  return f;
}
__device__ __forceinline__ unsigned int pk2(float x, float y) {
  return ((unsigned int)f2bf(x)) | (((unsigned int)f2bf(y)) << 16);
}

// ---- init bucket cursors ----------------------------------------------------
__global__ void k_binit(int* __restrict__ bcur) {
  int k = threadIdx.x;
  if (k < NB1) bcur[k] = k * CAPB;
}

// ---- S1: bin edges by col>>9; packed (row<<9)|col&511 writes ---------------
__global__ __launch_bounds__(256) void kS1(const int* __restrict__ rowi,
                                           const int* __restrict__ coli,
                                           int* __restrict__ bcur,
                                           unsigned int* __restrict__ binpk) {
  __shared__ int hist[NB1];
  __shared__ int base[NB1];
  const int t = threadIdx.x;
  const long long e0 = (long long)blockIdx.x * 4096;
  for (int i = t; i < NB1; i += 256) hist[i] = 0;
  __syncthreads();
  int r[16], c[16], b[16];
#pragma unroll
  for (int i = 0; i < 16; ++i) {
    long long e = e0 + t + i * 256;
    if (e < EDGES) {
      r[i] = rowi[e]; c[i] = coli[e]; b[i] = c[i] >> 9;
      atomicAdd(&hist[b[i]], 1);
    } else {
      b[i] = -1;
    }
  }
  __syncthreads();
  for (int i = t; i < NB1; i += 256)
    base[i] = hist[i] ? atomicAdd(&bcur[i], hist[i]) : 0;
  __syncthreads();
#pragma unroll
  for (int i = 0; i < 16; ++i) {
    if (b[i] >= 0) {
      int p = atomicAdd(&base[b[i]], 1);
      if (p < (b[i] + 1) * CAPB)
        binpk[p] = ((unsigned int)r[i] << 9) | (unsigned int)(c[i] & 511);
    }
  }
}

// ---- S2: per-bucket histogram + scan + LDS-cursor sort; emits CSR + dinv ----
__global__ __launch_bounds__(256) void kS2(const unsigned int* __restrict__ binpk,
                                           const int* __restrict__ bcur,
                                           int* __restrict__ srow,
                                           int* __restrict__ offs,
                                           int* __restrict__ cnt,
                                           float* __restrict__ dinv) {
  __shared__ int h[512];
  __shared__ int sc[256];
  const int k = blockIdx.x, t = threadIdx.x;
  const int beg = k * CAPB;
  const int c0 = k << 9;
  int n = bcur[k] - beg;
  if (n > CAPB) n = CAPB;
  h[t] = 0; h[t + 256] = 0;
  __syncthreads();
  for (int i = t; i < n; i += 256) atomicAdd(&h[binpk[beg + i] & 511u], 1);
  __syncthreads();
  int s0 = h[2 * t], s1 = h[2 * t + 1];
  sc[t] = s0 + s1;
  __syncthreads();
  for (int d = 1; d < 256; d <<= 1) {
    int v = (t >= d) ? sc[t - d] : 0;
    __syncthreads();
    sc[t] += v;
    __syncthreads();
  }
  int base2 = t ? sc[t - 1] : 0;
  int c = c0 + 2 * t;
  if (c < NODES) {
    offs[c] = beg + base2; cnt[c] = s0; dinv[c] = rsqrtf((float)(s0 + 1));
  }
  if (c + 1 < NODES) {
    offs[c + 1] = beg + base2 + s0; cnt[c + 1] = s1; dinv[c + 1] = rsqrtf((float)(s1 + 1));
  }
  __syncthreads();
  h[2 * t] = beg + base2;
  h[2 * t + 1] = beg + base2 + s0;
  __syncthreads();
  for (int i = t; i < n; i += 256) {
    unsigned int p = binpk[beg + i];
    int pos = atomicAdd(&h[p & 511u], 1);
    srow[pos] = (int)(p >> 9);
  }
}

// ---- MFMA GEMM layer1: HD[bf16] = bf16( (X*dinv_row)[f32->bf16] @ W1 ) ------
// 128x128 tile, K=128 one shot. 4 waves (2x2), wave = 64x64 (4x4 frags).
__global__ __launch_bounds__(256) void k_gemm1(const float* __restrict__ X,
                                               const float* __restrict__ W,
                                               const float* __restrict__ dinv,
                                               unsigned short* __restrict__ HD,
                                               int nrows) {
  __shared__ unsigned short As[128 * 128];
  __shared__ unsigned short Bs[128 * 128];
  const int t = threadIdx.x;
  const int r0 = blockIdx.x * 128;

  // stage A: X row-scaled by dinv, f32 -> bf16, swizzled 16B units
#pragma unroll
  for (int j = 0; j < 8; ++j) {
    int u = t + j * 256;
    int row = u >> 4, slot = u & 15;
    int gr = r0 + row;
    short8 v = {0, 0, 0, 0, 0, 0, 0, 0};
    if (gr < nrows) {
      float d = dinv[gr];
      const float4* px = (const float4*)(X + (long long)gr * 128 + slot * 8);
      float4 x0 = px[0], x1 = px[1];
      unsigned short tv[8];
      tv[0] = f2bf(x0.x * d); tv[1] = f2bf(x0.y * d);
      tv[2] = f2bf(x0.z * d); tv[3] = f2bf(x0.w * d);
      tv[4] = f2bf(x1.x * d); tv[5] = f2bf(x1.y * d);
      tv[6] = f2bf(x1.z * d); tv[7] = f2bf(x1.w * d);
      v = *(short8*)tv;
    }
    *(short8*)(&As[row * 128 + ((slot ^ (row & 7)) << 3)]) = v;
  }
  // stage B transposed: W[k][n] f32 -> Bs[n][k] bf16 (swizzled)
  for (int i = t; i < 128 * 32; i += 256) {
    int k = i >> 5, n4 = (i & 31) << 2;
    float4 w = *(const float4*)(W + k * 128 + n4);
    int sl = k >> 3, ko = k & 7;
    Bs[(n4 + 0) * 128 + ((sl ^ ((n4 + 0) & 7)) << 3) + ko] = f2bf(w.x);
    Bs[(n4 + 1) * 128 + ((sl ^ ((n4 + 1) & 7)) << 3) + ko] = f2bf(w.y);
    Bs[(n4 + 2) * 128 + ((sl ^ ((n4 + 2) & 7)) << 3) + ko] = f2bf(w.z);
    Bs[(n4 + 3) * 128 + ((sl ^ ((n4 + 3) & 7)) << 3) + ko] = f2bf(w.w);
  }
  __syncthreads();

  const int wid = t >> 6, l = t & 63;
  const int wm = (wid >> 1) * 64, wn = (wid & 1) * 64;
  const int lr = l & 15, lk = l >> 4;
  f32x4 acc[4][4];
#pragma unroll
  for (int mi = 0; mi < 4; ++mi)
#pragma unroll
    for (int ni = 0; ni < 4; ++ni) acc[mi][ni] = (f32x4){0.f, 0.f, 0.f, 0.f};

#pragma unroll
  for (int ks = 0; ks < 4; ++ks) {
    int slot = ks * 4 + lk;
    short8 a[4], b[4];
#pragma unroll
    for (int mi = 0; mi < 4; ++mi) {
      int row = wm + mi * 16 + lr;
      a[mi] = *(short8*)(&As[row * 128 + ((slot ^ (row & 7)) << 3)]);
    }
#pragma unroll
    for (int ni = 0; ni < 4; ++ni) {
      int row = wn + ni * 16 + lr;
      b[ni] = *(short8*)(&Bs[row * 128 + ((slot ^ (row & 7)) << 3)]);
    }
#pragma unroll
    for (int mi = 0; mi < 4; ++mi)
#pragma unroll
      for (int ni = 0; ni < 4; ++ni)
        acc[mi][ni] = __builtin_amdgcn_mfma_f32_16x16x32_bf16(a[mi], b[ni], acc[mi][ni], 0, 0, 0);
  }
  __syncthreads();

  // epilogue: bounce through As (linear), then coalesced bf16 stores
  const int lr4 = lk * 4;
#pragma unroll
  for (int mi = 0; mi < 4; ++mi)
#pragma unroll
    for (int ni = 0; ni < 4; ++ni)
#pragma unroll
      for (int r = 0; r < 4; ++r)
        As[(wm + mi * 16 + lr4 + r) * 128 + wn + ni * 16 + lr] = f2bf(acc[mi][ni][r]);
  __syncthreads();
#pragma unroll
  for (int j = 0; j < 8; ++j) {
    int u = t + j * 256;
    int row = u >> 4, slot = u & 15;
    int gr = r0 + row;
    if (gr < nrows)
      *(short8*)(HD + (long long)gr * 128 + slot * 8) = *(short8*)(&As[row * 128 + slot * 8]);
  }
}

// ---- MFMA GEMM layer2: HD2[bf16] = bf16( h1r[bf16, pre-scaled] @ W2 ) -------
// 128x64 tile, K=128. 4 waves, wave = 32x64 (2x4 frags).
__global__ __launch_bounds__(256) void k_gemm2(const unsigned short* __restrict__ H1,
                                               const float* __restrict__ W,
                                               unsigned short* __restrict__ HD2,
                                               int nrows) {
  __shared__ unsigned short As[128 * 128];
  __shared__ unsigned short Bs[64 * 128];
  const int t = threadIdx.x;
  const int r0 = blockIdx.x * 128;

#pragma unroll
  for (int j = 0; j < 8; ++j) {
    int u = t + j * 256;
    int row = u >> 4, slot = u & 15;
    int gr = r0 + row;
    short8 v = {0, 0, 0, 0, 0, 0, 0, 0};
    if (gr < nrows) v = *(const short8*)(H1 + (long long)gr * 128 + slot * 8);
    *(short8*)(&As[row * 128 + ((slot ^ (row & 7)) << 3)]) = v;
  }
  for (int i = t; i < 128 * 16; i += 256) {
    int k = i >> 4, n4 = (i & 15) << 2;
    float4 w = *(const float4*)(W + k * 64 + n4);
    int sl = k >> 3, ko = k & 7;
    Bs[(n4 + 0) * 128 + ((sl ^ ((n4 + 0) & 7)) << 3) + ko] = f2bf(w.x);
    Bs[(n4 + 1) * 128 + ((sl ^ ((n4 + 1) & 7)) << 3) + ko] = f2bf(w.y);
    Bs[(n4 + 2) * 128 + ((sl ^ ((n4 + 2) & 7)) << 3) + ko] = f2bf(w.z);
    Bs[(n4 + 3) * 128 + ((sl ^ ((n4 + 3) & 7)) << 3) + ko] = f2bf(w.w);
  }
  __syncthreads();

  const int wid = t >> 6, l = t & 63;
  const int wm = wid * 32;
  const int lr = l & 15, lk = l >> 4;
  f32x4 acc[2][4];
#pragma unroll
  for (int mi = 0; mi < 2; ++mi)
#pragma unroll
    for (int ni = 0; ni < 4; ++ni) acc[mi][ni] = (f32x4){0.f, 0.f, 0.f, 0.f};

#pragma unroll
  for (int ks = 0; ks < 4; ++ks) {
    int slot = ks * 4 + lk;
    short8 a[2], b[4];
#pragma unroll
    for (int mi = 0; mi < 2; ++mi) {
      int row = wm + mi * 16 + lr;
      a[mi] = *(short8*)(&As[row * 128 + ((slot ^ (row & 7)) << 3)]);
    }
#pragma unroll
    for (int ni = 0; ni < 4; ++ni) {
      int row = ni * 16 + lr;
      b[ni] = *(short8*)(&Bs[row * 128 + ((slot ^ (row & 7)) << 3)]);
    }
#pragma unroll
    for (int mi = 0; mi < 2; ++mi)
#pragma unroll
      for (int ni = 0; ni < 4; ++ni)
        acc[mi][ni] = __builtin_amdgcn_mfma_f32_16x16x32_bf16(a[mi], b[ni], acc[mi][ni], 0, 0, 0);
  }
  __syncthreads();

  const int lr4 = lk * 4;
#pragma unroll
  for (int mi = 0; mi < 2; ++mi)
#pragma unroll
    for (int ni = 0; ni < 4; ++ni)
#pragma unroll
      for (int r = 0; r < 4; ++r)
        As[(wm + mi * 16 + lr4 + r) * 64 + ni * 16 + lr] = f2bf(acc[mi][ni][r]);
  __syncthreads();
#pragma unroll
  for (int j = 0; j < 4; ++j) {
    int u = t + j * 256;
    int row = u >> 3, slot = u & 7;
    int gr = r0 + row;
    if (gr < nrows)
      *(short8*)(HD2 + (long long)gr * 64 + slot * 8) = *(short8*)(&As[row * 64 + slot * 8]);
  }
}

// ---- CSR aggregation, F=128 bf16 in / bf16 out (relu+bias, xdinv folded) ----
__global__ __launch_bounds__(256) void k_agg1(const unsigned short* __restrict__ hd,
                                              const int* __restrict__ srow,
                                              const int* __restrict__ offs,
                                              const int* __restrict__ cnt,
                                              const float* __restrict__ dinv,
                                              const float* __restrict__ b1,
                                              unsigned short* __restrict__ h1r) {
  int w = (blockIdx.x << 2) + (threadIdx.x >> 6);
  if (w >= NODES) return;
  int lane = threadIdx.x & 63;
  const unsigned int* H = (const unsigned int*)hd;
  float2 a0 = up2(H[(long long)w * 64 + lane]);  // self-loop
  float2 a1 = {0.f, 0.f}, a2 = {0.f, 0.f}, a3 = {0.f, 0.f};
  float2 a4 = {0.f, 0.f}, a5 = {0.f, 0.f}, a6 = {0.f, 0.f}, a7 = {0.f, 0.f};
  int off = offs[w], n = cnt[w];
  int j = 0;
  for (; j + 7 < n; j += 8) {
    int r0 = srow[off + j],     r1 = srow[off + j + 1];
    int r2 = srow[off + j + 2], r3 = srow[off + j + 3];
    int r4 = srow[off + j + 4], r5 = srow[off + j + 5];
    int r6 = srow[off + j + 6], r7 = srow[off + j + 7];
    float2 v0 = up2(H[(long long)r0 * 64 + lane]);
    float2 v1 = up2(H[(long long)r1 * 64 + lane]);
    float2 v2 = up2(H[(long long)r2 * 64 + lane]);
    float2 v3 = up2(H[(long long)r3 * 64 + lane]);
    float2 v4 = up2(H[(long long)r4 * 64 + lane]);
    float2 v5 = up2(H[(long long)r5 * 64 + lane]);
    float2 v6 = up2(H[(long long)r6 * 64 + lane]);
    float2 v7 = up2(H[(long long)r7 * 64 + lane]);
    a0.x += v0.x; a0.y += v0.y; a1.x += v1.x; a1.y += v1.y;
    a2.x += v2.x; a2.y += v2.y; a3.x += v3.x; a3.y += v3.y;
    a4.x += v4.x; a4.y += v4.y; a5.x += v5.x; a5.y += v5.y;
    a6.x += v6.x; a6.y += v6.y; a7.x += v7.x; a7.y += v7.y;
  }
  for (; j + 3 < n; j += 4) {
    int r0 = srow[off + j],     r1 = srow[off + j + 1];
    int r2 = srow[off + j + 2], r3 = srow[off + j + 3];
    float2 v0 = up2(H[(long long)r0 * 64 + lane]);
    float2 v1 = up2(H[(long long)r1 * 64 + lane]);
    float2 v2 = up2(H[(long long)r2 * 64 + lane]);
    float2 v3 = up2(H[(long long)r3 * 64 + lane]);
    a0.x += v0.x; a0.y += v0.y; a1.x += v1.x; a1.y += v1.y;
    a2.x += v2.x; a2.y += v2.y; a3.x += v3.x; a3.y += v3.y;
  }
  for (; j < n; ++j) {
    float2 v = up2(H[(long long)srow[off + j] * 64 + lane]);
    a0.x += v.x; a0.y += v.y;
  }
  float ax = ((a0.x + a1.x) + (a2.x + a3.x)) + ((a4.x + a5.x) + (a6.x + a7.x));
  float ay = ((a0.y + a1.y) + (a2.y + a3.y)) + ((a4.y + a5.y) + (a6.y + a7.y));
  float dc = dinv[w];
  float2 b = ((const float2*)b1)[lane];
  // store relu(out1) * dinv[w]  (pre-scales rows for layer-2 GEMM)
  float ox = fmaxf(fmaf(ax, dc, b.x), 0.f) * dc;
  float oy = fmaxf(fmaf(ay, dc, b.y), 0.f) * dc;
  ((unsigned int*)h1r)[(long long)w * 64 + lane] = pk2(ox, oy);
}

// ---- CSR aggregation, F=64 bf16 in / f32 out (final, no relu) ---------------
__global__ __launch_bounds__(256) void k_agg2(const unsigned short* __restrict__ hd,
                                              const int* __restrict__ srow,
                                              const int* __restrict__ offs,
                                              const int* __restrict__ cnt,
                                              const float* __restrict__ dinv,
                                              const float* __restrict__ b2,
                                              float* __restrict__ outp) {
  int w = (blockIdx.x << 2) + (threadIdx.x >> 6);
  if (w >= NODES) return;
  int lane = threadIdx.x & 63;
  float a0 = bf2f(hd[(long long)w * 64 + lane]);  // self-loop
  float a1 = 0.f, a2 = 0.f, a3 = 0.f, a4 = 0.f, a5 = 0.f, a6 = 0.f, a7 = 0.f;
  int off = offs[w], n = cnt[w];
  int j = 0;
  for (; j + 7 < n; j += 8) {
    int r0 = srow[off + j],     r1 = srow[off + j + 1];
    int r2 = srow[off + j + 2], r3 = srow[off + j + 3];
    int r4 = srow[off + j + 4], r5 = srow[off + j + 5];
    int r6 = srow[off + j + 6], r7 = srow[off + j + 7];
    a0 += bf2f(hd[(long long)r0 * 64 + lane]);
    a1 += bf2f(hd[(long long)r1 * 64 + lane]);
    a2 += bf2f(hd[(long long)r2 * 64 + lane]);
    a3 += bf2f(hd[(long long)r3 * 64 + lane]);
    a4 += bf2f(hd[(long long)r4 * 64 + lane]);
    a5 += bf2f(hd[(long long)r5 * 64 + lane]);
    a6 += bf2f(hd[(long long)r6 * 64 + lane]);
    a7 += bf2f(hd[(long long)r7 * 64 + lane]);
  }
  for (; j + 3 < n; j += 4) {
    int r0 = srow[off + j],     r1 = srow[off + j + 1];
    int r2 = srow[off + j + 2], r3 = srow[off + j + 3];
    a0 += bf2f(hd[(long long)r0 * 64 + lane]);
    a1 += bf2f(hd[(long long)r1 * 64 + lane]);
    a2 += bf2f(hd[(long long)r2 * 64 + lane]);
    a3 += bf2f(hd[(long long)r3 * 64 + lane]);
  }
  for (; j < n; ++j) a0 += bf2f(hd[(long long)srow[off + j] * 64 + lane]);
  float acc = ((a0 + a1) + (a2 + a3)) + ((a4 + a5) + (a6 + a7));
  outp[(long long)w * 64 + lane] = fmaf(acc, dinv[w], b2[lane]);
}

extern "C" void kernel_launch(void* const* d_in, const int* in_sizes, int n_in,
                              void* d_out, int out_size, void* d_ws, size_t ws_size,
                              hipStream_t stream) {
  const float* x  = (const float*)d_in[0];
  const int*   ei = (const int*)d_in[1];  // [2, E]: row then col
  const float* W1 = (const float*)d_in[2];
  const float* b1 = (const float*)d_in[3];
  const float* W2 = (const float*)d_in[4];
  const float* b2 = (const float*)d_in[5];
  float* out = (float*)d_out;

  float* ws   = (float*)d_ws;
  float* dinv = ws;                          // 100352 f
  int*  cnt   = (int*)(ws + 100352);         // 100352 i
  int*  offs  = cnt + 100352;                // 100352 i
  int*  bcur  = offs + 100352;               // 256 i
  int*  srow  = bcur + 256;                  // NB1*CAPB i (8MB)
  unsigned int* binpk = (unsigned int*)(srow + NB1 * CAPB);  // NB1*CAPB u32 (8MB)
  unsigned short* hd  = (unsigned short*)(binpk + NB1 * CAPB);  // NODES*128 bf16
  unsigned short* h1r = hd + (long long)NODES * 128;            // NODES*128 bf16

  const int* rowi = ei;
  const int* coli = ei + EDGES;

  // ---- CSR build ----
  k_binit<<<dim3(1), dim3(256), 0, stream>>>(bcur);
  kS1<<<dim3((EDGES + 4095) / 4096), dim3(256), 0, stream>>>(rowi, coli, bcur, binpk);
  kS2<<<dim3(NB1), dim3(256), 0, stream>>>(binpk, bcur, srow, offs, cnt, dinv);

  // ---- Layer 1 ----
  k_gemm1<<<dim3((NODES + 127) / 128), dim3(256), 0, stream>>>(x, W1, dinv, hd, NODES);
  k_agg1<<<dim3((NODES + 3) / 4), dim3(256), 0, stream>>>(hd, srow, offs, cnt, dinv, b1, h1r);

  // ---- Layer 2 ----
  k_gemm2<<<dim3((NODES + 127) / 128), dim3(256), 0, stream>>>(h1r, W2, hd, NODES);
  k_agg2<<<dim3((NODES + 3) / 4), dim3(256), 0, stream>>>(hd, srow, offs, cnt, dinv, b2, out);
}